// Round 2
// baseline (778.989 us; speedup 1.0000x reference)
//
#include <hip/hip_runtime.h>

typedef _Float16 f16;
typedef _Float16 f16x8 __attribute__((ext_vector_type(8)));
typedef _Float16 f16x4 __attribute__((ext_vector_type(4)));
typedef float f32x4 __attribute__((ext_vector_type(4)));

__device__ __forceinline__ void gld16(const void* g, void* l) {
    __builtin_amdgcn_global_load_lds(
        (const __attribute__((address_space(1))) void*)g,
        (__attribute__((address_space(3))) void*)l,
        16, 0, 0);
}

// ---------------- fp32 -> fp16 convert (vectorized) ----------------
__global__ __launch_bounds__(256) void f32_to_f16_vec(const float* __restrict__ in,
                                                      f16* __restrict__ out, long n4) {
    long i = (long)blockIdx.x * 256 + threadIdx.x;
    if (i < n4) {
        float4 v = ((const float4*)in)[i];
        f16x4 o = {(f16)v.x, (f16)v.y, (f16)v.z, (f16)v.w};
        ((f16x4*)out)[i] = o;
    }
}

// ---------------- BT GEMM: C[M,N] = A[M,K] * B[N,K]^T + bias ----------------
// 128x128 tile, BK=32, 4 waves each computing 64x64. m97 structure.
__global__ __launch_bounds__(256) void gemm_bt(const f16* __restrict__ A,
                                               const f16* __restrict__ B,
                                               const float* __restrict__ bias,
                                               float* __restrict__ Cf,
                                               f16* __restrict__ Ch,
                                               int M, int N, int K) {
    constexpr int BK = 32;
    __shared__ f16 As[128 * BK];
    __shared__ f16 Bs[128 * BK];
    const int tid = threadIdx.x;
    const int w = tid >> 6;
    const int lane = tid & 63;
    const int quad = lane >> 4;
    const int l16 = lane & 15;
    const long m0 = (long)blockIdx.y * 128;
    const long n0 = (long)blockIdx.x * 128;

    const int srow = lane >> 2;        // 0..15
    const int scol = (lane & 3) * 8;   // 0,8,16,24
    const f16* gA = A + (m0 + w * 32 + srow) * (long)K + scol;
    const f16* gB = B + (n0 + w * 32 + srow) * (long)K + scol;
    const int lb0 = __builtin_amdgcn_readfirstlane(w * 1024);
    const int lb1 = __builtin_amdgcn_readfirstlane(w * 1024 + 512);

    const int mw = (w >> 1) * 64;
    const int nw = (w & 1) * 64;

    f32x4 acc[4][4] = {};

    for (int k0 = 0; k0 < K; k0 += BK) {
        gld16(gA + k0, &As[lb0]);
        gld16(gA + (long)16 * K + k0, &As[lb1]);
        gld16(gB + k0, &Bs[lb0]);
        gld16(gB + (long)16 * K + k0, &Bs[lb1]);
        __syncthreads();
        f16x8 af[4], bf[4];
#pragma unroll
        for (int t = 0; t < 4; ++t)
            af[t] = *(const f16x8*)&As[(mw + t * 16 + l16) * BK + quad * 8];
#pragma unroll
        for (int t = 0; t < 4; ++t)
            bf[t] = *(const f16x8*)&Bs[(nw + t * 16 + l16) * BK + quad * 8];
#pragma unroll
        for (int mt = 0; mt < 4; ++mt)
#pragma unroll
            for (int nt = 0; nt < 4; ++nt)
                acc[mt][nt] = __builtin_amdgcn_mfma_f32_16x16x32_f16(
                    af[mt], bf[nt], acc[mt][nt], 0, 0, 0);
        __syncthreads();
    }

#pragma unroll
    for (int nt = 0; nt < 4; ++nt) {
        const long col = n0 + nw + nt * 16 + l16;
        const float bv = bias ? bias[col] : 0.f;
#pragma unroll
        for (int mt = 0; mt < 4; ++mt) {
#pragma unroll
            for (int r = 0; r < 4; ++r) {
                const long row = m0 + mw + mt * 16 + quad * 4 + r;
                const float v = acc[mt][nt][r] + bv;
                if (Ch) Ch[row * (long)N + col] = (f16)v;
                else    Cf[row * (long)N + col] = v;
            }
        }
    }
}

// ---------------- RMSNorm q in-place + k repacked to kc[bh][s][72] ----------------
// one thread per (b,s,h); fully vectorized f16x8 loads/stores.
__global__ __launch_bounds__(256) void qk_norm2(f16* __restrict__ qkv,
                                                const float* __restrict__ qg,
                                                const float* __restrict__ kg,
                                                f16* __restrict__ kc) {
    const int t = blockIdx.x * 256 + threadIdx.x;  // 0..262143
    const int h = t & 15;
    const long bs = t >> 4;
    f16* qp = qkv + bs * 3456 + h * 72;
    // --- q in place ---
    {
        f16x8 v[9];
        float ss = 0.f;
#pragma unroll
        for (int c = 0; c < 9; ++c) {
            v[c] = *(const f16x8*)(qp + c * 8);
#pragma unroll
            for (int j = 0; j < 8; ++j) { float f = (float)v[c][j]; ss += f * f; }
        }
        const float rs = rsqrtf(ss * (1.f / 72.f) + 1.1920928955078125e-7f);
#pragma unroll
        for (int c = 0; c < 9; ++c) {
            f16x8 o;
#pragma unroll
            for (int j = 0; j < 8; ++j) o[j] = (f16)((float)v[c][j] * rs * qg[c * 8 + j]);
            *(f16x8*)(qp + c * 8) = o;
        }
    }
    // --- k -> kc ---
    {
        const f16* kp = qp + 1152;
        f16* dst = kc + ((long)((bs >> 10) * 16 + h) * 1024 + (bs & 1023)) * 72;
        f16x8 v[9];
        float ss = 0.f;
#pragma unroll
        for (int c = 0; c < 9; ++c) {
            v[c] = *(const f16x8*)(kp + c * 8);
#pragma unroll
            for (int j = 0; j < 8; ++j) { float f = (float)v[c][j]; ss += f * f; }
        }
        const float rs = rsqrtf(ss * (1.f / 72.f) + 1.1920928955078125e-7f);
#pragma unroll
        for (int c = 0; c < 9; ++c) {
            f16x8 o;
#pragma unroll
            for (int j = 0; j < 8; ++j) o[j] = (f16)((float)v[c][j] * rs * kg[c * 8 + j]);
            *(f16x8*)(dst + c * 8) = o;
        }
    }
}

// ---------------- V transpose: qkv[b,s,2304+h*72+d] -> Vt[bh][72][1024] ----------------
__global__ __launch_bounds__(256) void vt_kernel(const f16* __restrict__ QKV,
                                                 f16* __restrict__ Vt) {
    __shared__ f16 tile[64][73];
    const int tid = threadIdx.x;
    const int bh = blockIdx.x;
    const int b = bh >> 4, h = bh & 15;
    const int s0 = blockIdx.y * 64;
    for (int idx = tid; idx < 64 * 72; idx += 256) {
        const int r = idx / 72, c = idx % 72;
        tile[r][c] = QKV[((long)(b * 1024 + s0 + r)) * 3456 + 2304 + h * 72 + c];
    }
    __syncthreads();
    for (int idx = tid; idx < 72 * 64; idx += 256) {
        const int d = idx >> 6, s = idx & 63;
        Vt[((long)bh * 72 + d) * 1024 + s0 + s] = tile[s][d];
    }
}

// ---------------- Flash attention ----------------
// grid (bh=256, qt=16); block 256 = 4 waves, each wave owns 16 Q rows.
// Q from qkv (strided rows, head offset); Kc: [bh][1024][72]; Vt: [bh][72][1024]
__global__ __launch_bounds__(256) void attn(const f16* __restrict__ QKV,
                                            const f16* __restrict__ Kc,
                                            const f16* __restrict__ Vt,
                                            f16* __restrict__ O) {
    constexpr int S = 1024;
    __shared__ f16 Ks[64 * 72];      // packed [s_local][72]
    __shared__ f16 Vs[80 * 64];      // [d][s_local]; rows 72..79 zeroed (pad)
    __shared__ f16 Ps[4 * 16 * 64];  // per-wave P tile [m][k]
    const int tid = threadIdx.x;
    const int w = tid >> 6, lane = tid & 63;
    const int quad = lane >> 4, l16 = lane & 15;
    const int bh = blockIdx.x;
    const int b = bh >> 4, h = bh & 15;
    const int q0 = blockIdx.y * 64;

    for (int i = tid; i < 8 * 64; i += 256) Vs[72 * 64 + i] = (f16)0.f;

    // Q fragments: rows q0+w*16+l16, head h, dims 0..71 (chunk 2 padded)
    const f16* qrow = QKV + ((long)(b * 1024 + q0 + w * 16 + l16)) * 3456 + h * 72;
    f16x8 qz = {};
    f16x8 qf[3];
    qf[0] = *(const f16x8*)(qrow + quad * 8);
    qf[1] = *(const f16x8*)(qrow + 32 + quad * 8);
    qf[2] = (quad == 0) ? *(const f16x8*)(qrow + 64) : qz;

    f32x4 o[5] = {};
    float m_r[4], l_r[4];
#pragma unroll
    for (int r = 0; r < 4; ++r) { m_r[r] = -3.0e38f; l_r[r] = 0.f; }

    const f16* gK = Kc + (long)bh * S * 72;
    const f16* gV = Vt + (long)bh * 72 * S;
    const float scale = 0.11785113019775792f;  // 1/sqrt(72)

    for (int s0 = 0; s0 < S; s0 += 64) {
        // stage K tile (contiguous 9216B) and Vt tile (72 rows x 128B)
        for (int ch = w; ch < 9; ch += 4) {
            const int lb = __builtin_amdgcn_readfirstlane(ch * 512);
            gld16(gK + (long)s0 * 72 + ch * 512 + lane * 8, &Ks[lb]);
            gld16(gV + ((long)(ch * 8 + (lane >> 3))) * S + s0 + (lane & 7) * 8, &Vs[lb]);
        }
        __syncthreads();

        // scores: 16 q rows x 64 k cols per wave
        f32x4 sc[4] = {};
#pragma unroll
        for (int nt = 0; nt < 4; ++nt) {
            const int srow = (nt * 16 + l16) * 72;
            f16x8 k0 = *(const f16x8*)&Ks[srow + quad * 8];
            f16x8 k1 = *(const f16x8*)&Ks[srow + 32 + quad * 8];
            f16x8 k2 = *(const f16x8*)&Ks[srow + 64];  // broadcast; quads>0 see junk * qf2=0
            sc[nt] = __builtin_amdgcn_mfma_f32_16x16x32_f16(qf[0], k0, sc[nt], 0, 0, 0);
            sc[nt] = __builtin_amdgcn_mfma_f32_16x16x32_f16(qf[1], k1, sc[nt], 0, 0, 0);
            sc[nt] = __builtin_amdgcn_mfma_f32_16x16x32_f16(qf[2], k2, sc[nt], 0, 0, 0);
        }
#pragma unroll
        for (int nt = 0; nt < 4; ++nt)
#pragma unroll
            for (int r = 0; r < 4; ++r) sc[nt][r] *= scale;

        // online softmax (q-row lives across the 16 l16 lanes of a quad)
        float mx[4], al[4], rs[4];
#pragma unroll
        for (int r = 0; r < 4; ++r)
            mx[r] = fmaxf(fmaxf(sc[0][r], sc[1][r]), fmaxf(sc[2][r], sc[3][r]));
#pragma unroll
        for (int off = 1; off <= 8; off <<= 1)
#pragma unroll
            for (int r = 0; r < 4; ++r) mx[r] = fmaxf(mx[r], __shfl_xor(mx[r], off));
#pragma unroll
        for (int r = 0; r < 4; ++r) {
            const float mn = fmaxf(m_r[r], mx[r]);
            al[r] = __expf(m_r[r] - mn);
            m_r[r] = mn;
            rs[r] = 0.f;
        }
#pragma unroll
        for (int nt = 0; nt < 4; ++nt)
#pragma unroll
            for (int r = 0; r < 4; ++r) {
                const float p = __expf(sc[nt][r] - m_r[r]);
                sc[nt][r] = p;
                rs[r] += p;
            }
#pragma unroll
        for (int off = 1; off <= 8; off <<= 1)
#pragma unroll
            for (int r = 0; r < 4; ++r) rs[r] += __shfl_xor(rs[r], off);
#pragma unroll
        for (int r = 0; r < 4; ++r) l_r[r] = l_r[r] * al[r] + rs[r];

        // P: C-layout -> LDS [m][k] (per-wave region, no barrier needed)
#pragma unroll
        for (int nt = 0; nt < 4; ++nt)
#pragma unroll
            for (int r = 0; r < 4; ++r)
                Ps[w * 1024 + (quad * 4 + r) * 64 + nt * 16 + l16] = (f16)sc[nt][r];

        // rescale O
#pragma unroll
        for (int vt = 0; vt < 5; ++vt)
#pragma unroll
            for (int r = 0; r < 4; ++r) o[vt][r] *= al[r];

        // PV: A = P [16 x 64], B = Vt tile [d][s_local]
        f16x8 pf0 = *(const f16x8*)&Ps[w * 1024 + l16 * 64 + quad * 8];
        f16x8 pf1 = *(const f16x8*)&Ps[w * 1024 + l16 * 64 + 32 + quad * 8];
#pragma unroll
        for (int vt = 0; vt < 5; ++vt) {
            f16x8 v0 = *(const f16x8*)&Vs[(vt * 16 + l16) * 64 + quad * 8];
            f16x8 v1 = *(const f16x8*)&Vs[(vt * 16 + l16) * 64 + 32 + quad * 8];
            o[vt] = __builtin_amdgcn_mfma_f32_16x16x32_f16(pf0, v0, o[vt], 0, 0, 0);
            o[vt] = __builtin_amdgcn_mfma_f32_16x16x32_f16(pf1, v1, o[vt], 0, 0, 0);
        }
        __syncthreads();
    }

    // epilogue: O / l -> ao[b*1024+s][h*72+d] fp16
    float inv[4];
#pragma unroll
    for (int r = 0; r < 4; ++r) inv[r] = 1.f / l_r[r];
#pragma unroll
    for (int vt = 0; vt < 5; ++vt) {
        const int d = vt * 16 + l16;
        if (d < 72) {
#pragma unroll
            for (int r = 0; r < 4; ++r) {
                const long row = (long)b * 1024 + q0 + w * 16 + quad * 4 + r;
                O[row * 1152 + h * 72 + d] = (f16)(o[vt][r] * inv[r]);
            }
        }
    }
}

extern "C" void kernel_launch(void* const* d_in, const int* in_sizes, int n_in,
                              void* d_out, int out_size, void* d_ws, size_t ws_size,
                              hipStream_t stream) {
    const float* x       = (const float*)d_in[0];
    const float* w_qkv   = (const float*)d_in[1];
    const float* b_qkv   = (const float*)d_in[2];
    const float* q_gamma = (const float*)d_in[3];
    const float* k_gamma = (const float*)d_in[4];
    const float* w_proj  = (const float*)d_in[5];
    const float* b_proj  = (const float*)d_in[6];
    float* out = (float*)d_out;

    // workspace layout: 161,611,776 bytes total
    char* p = (char*)d_ws;
    f16* x_h = (f16*)p;      p += (size_t)16384 * 1152 * 2;  // reused as ao after QKV GEMM
    f16* wqkv_h = (f16*)p;   p += (size_t)3456 * 1152 * 2;
    f16* wproj_h = (f16*)p;  p += (size_t)1152 * 1152 * 2;
    f16* qkv_h = (f16*)p;    p += (size_t)16384 * 3456 * 2;
    const size_t needed = (size_t)(p - (char*)d_ws);
    if (ws_size < needed) return;  // diagnostic: clean absmax failure instead of a fault

    // d_out doubles as scratch until the final proj GEMM overwrites it (stream-ordered):
    f16* k_c = (f16*)d_out;                       // [256][1024][72] = 37,748,736 B
    f16* v_t = (f16*)d_out + (size_t)16384 * 1152; // [256][72][1024] = 37,748,736 B

    f32_to_f16_vec<<<18432, 256, 0, stream>>>(x, x_h, 16384L * 1152 / 4);
    f32_to_f16_vec<<<3888, 256, 0, stream>>>(w_qkv, wqkv_h, 3456L * 1152 / 4);
    f32_to_f16_vec<<<1296, 256, 0, stream>>>(w_proj, wproj_h, 1152L * 1152 / 4);

    gemm_bt<<<dim3(3456 / 128, 16384 / 128), 256, 0, stream>>>(
        x_h, wqkv_h, b_qkv, nullptr, qkv_h, 16384, 3456, 1152);

    qk_norm2<<<1024, 256, 0, stream>>>(qkv_h, q_gamma, k_gamma, k_c);
    vt_kernel<<<dim3(256, 16), 256, 0, stream>>>(qkv_h, v_t);

    attn<<<dim3(256, 16), 256, 0, stream>>>(qkv_h, k_c, v_t, x_h /* ao */);

    gemm_bt<<<dim3(1152 / 128, 16384 / 128), 256, 0, stream>>>(
        x_h, wproj_h, b_proj, out, nullptr, 16384, 1152, 1152);
}

// Round 3
// 620.902 us; speedup vs baseline: 1.2546x; 1.2546x over previous
//
#include <hip/hip_runtime.h>

typedef _Float16 f16;
typedef _Float16 f16x8 __attribute__((ext_vector_type(8)));
typedef _Float16 f16x4 __attribute__((ext_vector_type(4)));
typedef float f32x4 __attribute__((ext_vector_type(4)));

__device__ __forceinline__ void gld16(const void* g, void* l) {
    __builtin_amdgcn_global_load_lds(
        (const __attribute__((address_space(1))) void*)g,
        (__attribute__((address_space(3))) void*)l,
        16, 0, 0);
}

// ---------------- fp32 -> fp16 convert (vectorized) ----------------
__global__ __launch_bounds__(256) void f32_to_f16_vec(const float* __restrict__ in,
                                                      f16* __restrict__ out, long n4) {
    long i = (long)blockIdx.x * 256 + threadIdx.x;
    if (i < n4) {
        float4 v = ((const float4*)in)[i];
        f16x4 o = {(f16)v.x, (f16)v.y, (f16)v.z, (f16)v.w};
        ((f16x4*)out)[i] = o;
    }
}

// ---------------- BT GEMM: C[M,N] = A[M,K] * B[N,K]^T + bias ----------------
__global__ __launch_bounds__(256) void gemm_bt(const f16* __restrict__ A,
                                               const f16* __restrict__ B,
                                               const float* __restrict__ bias,
                                               float* __restrict__ Cf,
                                               f16* __restrict__ Ch,
                                               int M, int N, int K) {
    constexpr int BK = 32;
    __shared__ f16 As[128 * BK];
    __shared__ f16 Bs[128 * BK];
    const int tid = threadIdx.x;
    const int w = tid >> 6;
    const int lane = tid & 63;
    const int quad = lane >> 4;
    const int l16 = lane & 15;
    const long m0 = (long)blockIdx.y * 128;
    const long n0 = (long)blockIdx.x * 128;

    const int srow = lane >> 2;        // 0..15
    const int scol = (lane & 3) * 8;   // 0,8,16,24
    const f16* gA = A + (m0 + w * 32 + srow) * (long)K + scol;
    const f16* gB = B + (n0 + w * 32 + srow) * (long)K + scol;
    const int lb0 = __builtin_amdgcn_readfirstlane(w * 1024);
    const int lb1 = __builtin_amdgcn_readfirstlane(w * 1024 + 512);

    const int mw = (w >> 1) * 64;
    const int nw = (w & 1) * 64;

    f32x4 acc[4][4] = {};

    for (int k0 = 0; k0 < K; k0 += BK) {
        gld16(gA + k0, &As[lb0]);
        gld16(gA + (long)16 * K + k0, &As[lb1]);
        gld16(gB + k0, &Bs[lb0]);
        gld16(gB + (long)16 * K + k0, &Bs[lb1]);
        __syncthreads();
        f16x8 af[4], bf[4];
#pragma unroll
        for (int t = 0; t < 4; ++t)
            af[t] = *(const f16x8*)&As[(mw + t * 16 + l16) * BK + quad * 8];
#pragma unroll
        for (int t = 0; t < 4; ++t)
            bf[t] = *(const f16x8*)&Bs[(nw + t * 16 + l16) * BK + quad * 8];
#pragma unroll
        for (int mt = 0; mt < 4; ++mt)
#pragma unroll
            for (int nt = 0; nt < 4; ++nt)
                acc[mt][nt] = __builtin_amdgcn_mfma_f32_16x16x32_f16(
                    af[mt], bf[nt], acc[mt][nt], 0, 0, 0);
        __syncthreads();
    }

#pragma unroll
    for (int nt = 0; nt < 4; ++nt) {
        const long col = n0 + nw + nt * 16 + l16;
        const float bv = bias ? bias[col] : 0.f;
#pragma unroll
        for (int mt = 0; mt < 4; ++mt) {
#pragma unroll
            for (int r = 0; r < 4; ++r) {
                const long row = m0 + mw + mt * 16 + quad * 4 + r;
                const float v = acc[mt][nt][r] + bv;
                if (Ch) Ch[row * (long)N + col] = (f16)v;
                else    Cf[row * (long)N + col] = v;
            }
        }
    }
}

// ---------------- RMSNorm q in-place (x attn scale) + k repacked to kc[bh][s][72] ----------------
__global__ __launch_bounds__(256) void qk_norm2(f16* __restrict__ qkv,
                                                const float* __restrict__ qg,
                                                const float* __restrict__ kg,
                                                f16* __restrict__ kc) {
    const float QSCALE = 0.117851130198f;  // 1/sqrt(72), folded into q
    const int t = blockIdx.x * 256 + threadIdx.x;  // 0..262143
    const int h = t & 15;
    const long bs = t >> 4;
    f16* qp = qkv + bs * 3456 + h * 72;
    {
        f16x8 v[9];
        float ss = 0.f;
#pragma unroll
        for (int c = 0; c < 9; ++c) {
            v[c] = *(const f16x8*)(qp + c * 8);
#pragma unroll
            for (int j = 0; j < 8; ++j) { float f = (float)v[c][j]; ss += f * f; }
        }
        const float rs = rsqrtf(ss * (1.f / 72.f) + 1.1920928955078125e-7f) * QSCALE;
#pragma unroll
        for (int c = 0; c < 9; ++c) {
            f16x8 o;
#pragma unroll
            for (int j = 0; j < 8; ++j) o[j] = (f16)((float)v[c][j] * rs * qg[c * 8 + j]);
            *(f16x8*)(qp + c * 8) = o;
        }
    }
    {
        const f16* kp = qp + 1152;
        f16* dst = kc + ((long)((bs >> 10) * 16 + h) * 1024 + (bs & 1023)) * 72;
        f16x8 v[9];
        float ss = 0.f;
#pragma unroll
        for (int c = 0; c < 9; ++c) {
            v[c] = *(const f16x8*)(kp + c * 8);
#pragma unroll
            for (int j = 0; j < 8; ++j) { float f = (float)v[c][j]; ss += f * f; }
        }
        const float rs = rsqrtf(ss * (1.f / 72.f) + 1.1920928955078125e-7f);
#pragma unroll
        for (int c = 0; c < 9; ++c) {
            f16x8 o;
#pragma unroll
            for (int j = 0; j < 8; ++j) o[j] = (f16)((float)v[c][j] * rs * kg[c * 8 + j]);
            *(f16x8*)(dst + c * 8) = o;
        }
    }
}

// ---------------- V transpose: qkv[b,s,2304+h*72+d] -> Vt[bh][72][1024] ----------------
__global__ __launch_bounds__(256) void vt_kernel(const f16* __restrict__ QKV,
                                                 f16* __restrict__ Vt) {
    __shared__ f16 tile[64][73];
    const int tid = threadIdx.x;
    const int bh = blockIdx.x;
    const int b = bh >> 4, h = bh & 15;
    const int s0 = blockIdx.y * 64;
    for (int idx = tid; idx < 64 * 72; idx += 256) {
        const int r = idx / 72, c = idx % 72;
        tile[r][c] = QKV[((long)(b * 1024 + s0 + r)) * 3456 + 2304 + h * 72 + c];
    }
    __syncthreads();
    for (int idx = tid; idx < 72 * 64; idx += 256) {
        const int d = idx >> 6, s = idx & 63;
        Vt[((long)bh * 72 + d) * 1024 + s0 + s] = tile[s][d];
    }
}

// ---------------- Flash attention v2 ----------------
// grid 2048 (XCD-swizzled); block 256 = 4 waves; each block does 128 q rows,
// each wave 32 (2 MFMA col-tiles). Sc^T = K·Q^T so P^T stays in registers as
// the B-fragment of mfma_16x16x16; O^T accumulated; l via ones-row of V.
__global__ __launch_bounds__(256) void attn2(const f16* __restrict__ QKV,
                                             const f16* __restrict__ Kc,
                                             const f16* __restrict__ Vt,
                                             f16* __restrict__ O) {
    constexpr int S = 1024;
    __shared__ f16 smem[64 * 72 + 80 * 76];  // Ks | Vs(padded), 21376 B
    f16* Ks = smem;
    f16* Vs = smem + 64 * 72;
    const int tid = threadIdx.x;
    const int w = tid >> 6, lane = tid & 63;
    const int quad = lane >> 4, l16 = lane & 15;

    // XCD swizzle: qt fastest within a bh, bh group-of-8 per XCD
    const int b = blockIdx.x;
    const int xcd = b & 7;
    const int j = b >> 3;
    const int bh = ((j >> 3) << 3) | xcd;
    const int qt = j & 7;
    const int bb = bh >> 4, h = bh & 15;
    const int q0 = qt * 128;

    // pad rows of Vs: row 72 = ones (l-accumulator), rows 73..79 = 0
    for (int i = tid; i < 8 * 76; i += 256) {
        const int pr = i / 76, pc = i % 76;
        Vs[(72 + pr) * 76 + pc] = (pr == 0 && pc < 64) ? (f16)1.f : (f16)0.f;
    }

    // Q fragments (q pre-scaled by 1/sqrt(72) in qk_norm2); chunk2 zero-padded
    const f16* qrow0 = QKV + ((long)(bb * 1024 + q0 + w * 32 + l16)) * 3456 + h * 72;
    const f16* qrow1 = qrow0 + (long)16 * 3456;
    f16x8 qz = {};
    f16x8 qf[2][3];
    qf[0][0] = *(const f16x8*)(qrow0 + quad * 8);
    qf[0][1] = *(const f16x8*)(qrow0 + 32 + quad * 8);
    qf[0][2] = (quad == 0) ? *(const f16x8*)(qrow0 + 64) : qz;
    qf[1][0] = *(const f16x8*)(qrow1 + quad * 8);
    qf[1][1] = *(const f16x8*)(qrow1 + 32 + quad * 8);
    qf[1][2] = (quad == 0) ? *(const f16x8*)(qrow1 + 64) : qz;

    f32x4 o[2][5] = {};

    const f16* gK = Kc + (long)bh * S * 72;
    const f16* gV = Vt + (long)bh * 72 * S;

    for (int s0 = 0; s0 < S; s0 += 64) {
        // stage K tile (contiguous 9216 B) via global_load_lds
        for (int ch = w; ch < 9; ch += 4)
            gld16(gK + (long)s0 * 72 + ch * 512 + lane * 8,
                  &Ks[__builtin_amdgcn_readfirstlane(ch * 512)]);
        // stage V tile into padded rows (76) via regs
#pragma unroll
        for (int it = 0; it < 3; ++it) {
            const int idx = it * 256 + tid;
            if (idx < 576) {
                const int d = idx >> 3, s8 = (idx & 7) * 8;
                f16x8 v = *(const f16x8*)(gV + (long)d * 1024 + s0 + s8);
                f16x4 lo = {v[0], v[1], v[2], v[3]};
                f16x4 hi = {v[4], v[5], v[6], v[7]};
                *(f16x4*)&Vs[d * 76 + s8] = lo;
                *(f16x4*)&Vs[d * 76 + s8 + 4] = hi;
            }
        }
        __syncthreads();

        // Sc^T[s][q] = K·Q^T : A=K-frag, B=Q-frag
        f32x4 sc[4][2] = {};
#pragma unroll
        for (int ss = 0; ss < 4; ++ss) {
            const int base = (ss * 16 + l16) * 72;
            f16x8 k0 = *(const f16x8*)&Ks[base + quad * 8];
            f16x8 k1 = *(const f16x8*)&Ks[base + 32 + quad * 8];
            f16x8 k2 = *(const f16x8*)&Ks[base + 64 + quad * 8];  // junk for quad>0: q-frag is 0
            sc[ss][0] = __builtin_amdgcn_mfma_f32_16x16x32_f16(k0, qf[0][0], sc[ss][0], 0, 0, 0);
            sc[ss][0] = __builtin_amdgcn_mfma_f32_16x16x32_f16(k1, qf[0][1], sc[ss][0], 0, 0, 0);
            sc[ss][0] = __builtin_amdgcn_mfma_f32_16x16x32_f16(k2, qf[0][2], sc[ss][0], 0, 0, 0);
            sc[ss][1] = __builtin_amdgcn_mfma_f32_16x16x32_f16(k0, qf[1][0], sc[ss][1], 0, 0, 0);
            sc[ss][1] = __builtin_amdgcn_mfma_f32_16x16x32_f16(k1, qf[1][1], sc[ss][1], 0, 0, 0);
            sc[ss][1] = __builtin_amdgcn_mfma_f32_16x16x32_f16(k2, qf[1][2], sc[ss][1], 0, 0, 0);
        }

        // p = exp(s) — no max subtraction: |s| <= sqrt(72) ~ 8.5, exp <= ~4900
        f16x4 pf[4][2];
#pragma unroll
        for (int ss = 0; ss < 4; ++ss)
#pragma unroll
            for (int qs = 0; qs < 2; ++qs) {
                f16x4 pk;
#pragma unroll
                for (int r = 0; r < 4; ++r) pk[r] = (f16)__expf(sc[ss][qs][r]);
                pf[ss][qs] = pk;
            }

        // O^T[d][q] += Vt_frag · P^T   (16x16x16, K = s)
#pragma unroll
        for (int vt = 0; vt < 5; ++vt) {
#pragma unroll
            for (int ss = 0; ss < 4; ++ss) {
                f16x4 vf = *(const f16x4*)&Vs[(vt * 16 + l16) * 76 + ss * 16 + quad * 4];
                o[0][vt] = __builtin_amdgcn_mfma_f32_16x16x16f16(vf, pf[ss][0], o[0][vt], 0, 0, 0);
                o[1][vt] = __builtin_amdgcn_mfma_f32_16x16x16f16(vf, pf[ss][1], o[1][vt], 0, 0, 0);
            }
        }
        __syncthreads();
    }

    // l lives at d==72 -> (vt=4, quad=2, r=0); broadcast per q column
    const float l0 = __shfl(o[0][4][0], 32 + l16);
    const float l1 = __shfl(o[1][4][0], 32 + l16);
    const float inv[2] = {1.f / l0, 1.f / l1};

    // transpose O^T -> O via per-wave LDS scratch (rows of 80), then coalesced stores
    f16* es = smem + w * 2560;  // 32 rows x 80
#pragma unroll
    for (int qs = 0; qs < 2; ++qs) {
        f16* row = es + (qs * 16 + l16) * 80;
#pragma unroll
        for (int vt = 0; vt < 5; ++vt)
#pragma unroll
            for (int r = 0; r < 4; ++r) {
                const int d = vt * 16 + quad * 4 + r;
                if (d < 72) row[d] = (f16)(o[qs][vt][r] * inv[qs]);
            }
    }
    const long rowbase = (long)bb * 1024 + q0 + w * 32;
#pragma unroll
    for (int it = 0; it < 5; ++it) {
        const int idx = it * 64 + lane;
        if (idx < 288) {
            const int q = idx / 9, c = idx - q * 9;
            f16x4 a = *(const f16x4*)&es[q * 80 + c * 8];
            f16x4 b2 = *(const f16x4*)&es[q * 80 + c * 8 + 4];
            f16* dst = O + (rowbase + q) * 1152 + h * 72 + c * 8;
            *(f16x4*)dst = a;
            *(f16x4*)(dst + 4) = b2;
        }
    }
}

extern "C" void kernel_launch(void* const* d_in, const int* in_sizes, int n_in,
                              void* d_out, int out_size, void* d_ws, size_t ws_size,
                              hipStream_t stream) {
    const float* x       = (const float*)d_in[0];
    const float* w_qkv   = (const float*)d_in[1];
    const float* b_qkv   = (const float*)d_in[2];
    const float* q_gamma = (const float*)d_in[3];
    const float* k_gamma = (const float*)d_in[4];
    const float* w_proj  = (const float*)d_in[5];
    const float* b_proj  = (const float*)d_in[6];
    float* out = (float*)d_out;

    char* p = (char*)d_ws;
    f16* x_h = (f16*)p;      p += (size_t)16384 * 1152 * 2;  // reused as ao after QKV GEMM
    f16* wqkv_h = (f16*)p;   p += (size_t)3456 * 1152 * 2;
    f16* wproj_h = (f16*)p;  p += (size_t)1152 * 1152 * 2;
    f16* qkv_h = (f16*)p;    p += (size_t)16384 * 3456 * 2;
    const size_t needed = (size_t)(p - (char*)d_ws);
    if (ws_size < needed) return;

    // d_out doubles as scratch until the final proj GEMM overwrites it:
    f16* k_c = (f16*)d_out;                        // [256][1024][72]
    f16* v_t = (f16*)d_out + (size_t)16384 * 1152; // [256][72][1024]

    f32_to_f16_vec<<<18432, 256, 0, stream>>>(x, x_h, 16384L * 1152 / 4);
    f32_to_f16_vec<<<3888, 256, 0, stream>>>(w_qkv, wqkv_h, 3456L * 1152 / 4);
    f32_to_f16_vec<<<1296, 256, 0, stream>>>(w_proj, wproj_h, 1152L * 1152 / 4);

    gemm_bt<<<dim3(3456 / 128, 16384 / 128), 256, 0, stream>>>(
        x_h, wqkv_h, b_qkv, nullptr, qkv_h, 16384, 3456, 1152);

    qk_norm2<<<1024, 256, 0, stream>>>(qkv_h, q_gamma, k_gamma, k_c);
    vt_kernel<<<dim3(256, 16), 256, 0, stream>>>(qkv_h, v_t);

    attn2<<<2048, 256, 0, stream>>>(qkv_h, k_c, v_t, x_h /* ao */);

    gemm_bt<<<dim3(1152 / 128, 16384 / 128), 256, 0, stream>>>(
        x_h, wproj_h, b_proj, out, nullptr, 16384, 1152, 1152);
}

// Round 4
// 584.114 us; speedup vs baseline: 1.3336x; 1.0630x over previous
//
#include <hip/hip_runtime.h>

typedef _Float16 f16;
typedef _Float16 f16x8 __attribute__((ext_vector_type(8)));
typedef _Float16 f16x4 __attribute__((ext_vector_type(4)));
typedef float f32x4 __attribute__((ext_vector_type(4)));

__device__ __forceinline__ void gld16(const void* g, void* l) {
    __builtin_amdgcn_global_load_lds(
        (const __attribute__((address_space(1))) void*)g,
        (__attribute__((address_space(3))) void*)l,
        16, 0, 0);
}

// ---------------- fp32 -> fp16 convert (vectorized) ----------------
__global__ __launch_bounds__(256) void f32_to_f16_vec(const float* __restrict__ in,
                                                      f16* __restrict__ out, long n4) {
    long i = (long)blockIdx.x * 256 + threadIdx.x;
    if (i < n4) {
        float4 v = ((const float4*)in)[i];
        f16x4 o = {(f16)v.x, (f16)v.y, (f16)v.z, (f16)v.w};
        ((f16x4*)out)[i] = o;
    }
}

// ---------------- BT GEMM: C[M,N] = A[M,K] * B[N,K]^T + bias ----------------
// 128x128 tile, BK=32, 4 waves each 64x64. 1D grid, XCD-banded swizzle:
// xcd = id&7 (round-robin heuristic); each XCD owns mblk/64 private M-bands of
// 8 blocks (A band 2.36 MB, L2-resident) and sweeps N panels across them.
__global__ __launch_bounds__(256) void gemm_bt(const f16* __restrict__ A,
                                               const f16* __restrict__ B,
                                               const float* __restrict__ bias,
                                               float* __restrict__ Cf,
                                               f16* __restrict__ Ch,
                                               int M, int N, int K) {
    constexpr int BK = 32;
    __shared__ f16 As[128 * BK];
    __shared__ f16 Bs[128 * BK];
    const int tid = threadIdx.x;
    const int w = tid >> 6;
    const int lane = tid & 63;
    const int quad = lane >> 4;
    const int l16 = lane & 15;

    // ---- XCD-banded block swizzle (requires M%1024==0, grid%8==0) ----
    const int nblk = N >> 7;
    const int mblk = M >> 7;
    const int id = blockIdx.x;
    const int xcd = id & 7;
    const int s = id >> 3;
    const int per_band = nblk * 8;          // blocks per band sweep
    const int t = s / per_band;             // band ordinal within this XCD
    const int r0 = s - t * per_band;
    const int n_blk = r0 >> 3;
    const int mr = r0 & 7;
    const int bands_per_xcd = mblk >> 6;    // mblk/8/8
    const int m_blk = (xcd * bands_per_xcd + t) * 8 + mr;

    const long m0 = (long)m_blk * 128;
    const long n0 = (long)n_blk * 128;

    const int srow = lane >> 2;        // 0..15
    const int scol = (lane & 3) * 8;   // 0,8,16,24
    const f16* gA = A + (m0 + w * 32 + srow) * (long)K + scol;
    const f16* gB = B + (n0 + w * 32 + srow) * (long)K + scol;
    const int lb0 = __builtin_amdgcn_readfirstlane(w * 1024);
    const int lb1 = __builtin_amdgcn_readfirstlane(w * 1024 + 512);

    const int mw = (w >> 1) * 64;
    const int nw = (w & 1) * 64;

    f32x4 acc[4][4] = {};

    for (int k0 = 0; k0 < K; k0 += BK) {
        gld16(gA + k0, &As[lb0]);
        gld16(gA + (long)16 * K + k0, &As[lb1]);
        gld16(gB + k0, &Bs[lb0]);
        gld16(gB + (long)16 * K + k0, &Bs[lb1]);
        __syncthreads();
        f16x8 af[4], bf[4];
#pragma unroll
        for (int t2 = 0; t2 < 4; ++t2)
            af[t2] = *(const f16x8*)&As[(mw + t2 * 16 + l16) * BK + quad * 8];
#pragma unroll
        for (int t2 = 0; t2 < 4; ++t2)
            bf[t2] = *(const f16x8*)&Bs[(nw + t2 * 16 + l16) * BK + quad * 8];
#pragma unroll
        for (int mt = 0; mt < 4; ++mt)
#pragma unroll
            for (int nt = 0; nt < 4; ++nt)
                acc[mt][nt] = __builtin_amdgcn_mfma_f32_16x16x32_f16(
                    af[mt], bf[nt], acc[mt][nt], 0, 0, 0);
        __syncthreads();
    }

    // epilogue: row-major emit, nt innermost so the two 32B halves of each
    // 64B C-line issue back-to-back (write-combine, no partial writebacks)
    float bv[4];
#pragma unroll
    for (int nt = 0; nt < 4; ++nt)
        bv[nt] = bias ? bias[n0 + nw + nt * 16 + l16] : 0.f;
#pragma unroll
    for (int mt = 0; mt < 4; ++mt) {
#pragma unroll
        for (int r = 0; r < 4; ++r) {
            const long row = m0 + mw + mt * 16 + quad * 4 + r;
#pragma unroll
            for (int nt = 0; nt < 4; ++nt) {
                const long col = n0 + nw + nt * 16 + l16;
                const float v = acc[mt][nt][r] + bv[nt];
                if (Ch) Ch[row * (long)N + col] = (f16)v;
                else    Cf[row * (long)N + col] = v;
            }
        }
    }
}

// ---------------- RMSNorm q in-place (x attn scale) + k repacked to kc[bh][s][72] ----------------
__global__ __launch_bounds__(256) void qk_norm2(f16* __restrict__ qkv,
                                                const float* __restrict__ qg,
                                                const float* __restrict__ kg,
                                                f16* __restrict__ kc) {
    const float QSCALE = 0.117851130198f;  // 1/sqrt(72), folded into q
    const int t = blockIdx.x * 256 + threadIdx.x;  // 0..262143
    const int h = t & 15;
    const long bs = t >> 4;
    f16* qp = qkv + bs * 3456 + h * 72;
    {
        f16x8 v[9];
        float ss = 0.f;
#pragma unroll
        for (int c = 0; c < 9; ++c) {
            v[c] = *(const f16x8*)(qp + c * 8);
#pragma unroll
            for (int j = 0; j < 8; ++j) { float f = (float)v[c][j]; ss += f * f; }
        }
        const float rs = rsqrtf(ss * (1.f / 72.f) + 1.1920928955078125e-7f) * QSCALE;
#pragma unroll
        for (int c = 0; c < 9; ++c) {
            f16x8 o;
#pragma unroll
            for (int j = 0; j < 8; ++j) o[j] = (f16)((float)v[c][j] * rs * qg[c * 8 + j]);
            *(f16x8*)(qp + c * 8) = o;
        }
    }
    {
        const f16* kp = qp + 1152;
        f16* dst = kc + ((long)((bs >> 10) * 16 + h) * 1024 + (bs & 1023)) * 72;
        f16x8 v[9];
        float ss = 0.f;
#pragma unroll
        for (int c = 0; c < 9; ++c) {
            v[c] = *(const f16x8*)(kp + c * 8);
#pragma unroll
            for (int j = 0; j < 8; ++j) { float f = (float)v[c][j]; ss += f * f; }
        }
        const float rs = rsqrtf(ss * (1.f / 72.f) + 1.1920928955078125e-7f);
#pragma unroll
        for (int c = 0; c < 9; ++c) {
            f16x8 o;
#pragma unroll
            for (int j = 0; j < 8; ++j) o[j] = (f16)((float)v[c][j] * rs * kg[c * 8 + j]);
            *(f16x8*)(dst + c * 8) = o;
        }
    }
}

// ---------------- V transpose: qkv[b,s,2304+h*72+d] -> Vt[bh][72][1024] ----------------
__global__ __launch_bounds__(256) void vt_kernel(const f16* __restrict__ QKV,
                                                 f16* __restrict__ Vt) {
    __shared__ f16 tile[64][73];
    const int tid = threadIdx.x;
    const int bh = blockIdx.x;
    const int b = bh >> 4, h = bh & 15;
    const int s0 = blockIdx.y * 64;
    for (int idx = tid; idx < 64 * 72; idx += 256) {
        const int r = idx / 72, c = idx % 72;
        tile[r][c] = QKV[((long)(b * 1024 + s0 + r)) * 3456 + 2304 + h * 72 + c];
    }
    __syncthreads();
    for (int idx = tid; idx < 72 * 64; idx += 256) {
        const int d = idx >> 6, s = idx & 63;
        Vt[((long)bh * 72 + d) * 1024 + s0 + s] = tile[s][d];
    }
}

// ---------------- Flash attention v2 ----------------
__global__ __launch_bounds__(256) void attn2(const f16* __restrict__ QKV,
                                             const f16* __restrict__ Kc,
                                             const f16* __restrict__ Vt,
                                             f16* __restrict__ O) {
    constexpr int S = 1024;
    __shared__ f16 smem[64 * 72 + 80 * 76];  // Ks | Vs(padded), 21376 B
    f16* Ks = smem;
    f16* Vs = smem + 64 * 72;
    const int tid = threadIdx.x;
    const int w = tid >> 6, lane = tid & 63;
    const int quad = lane >> 4, l16 = lane & 15;

    // XCD swizzle: qt fastest within a bh, bh group-of-8 per XCD
    const int b = blockIdx.x;
    const int xcd = b & 7;
    const int j = b >> 3;
    const int bh = ((j >> 3) << 3) | xcd;
    const int qt = j & 7;
    const int bb = bh >> 4, h = bh & 15;
    const int q0 = qt * 128;

    // pad rows of Vs: row 72 = ones (l-accumulator), rows 73..79 = 0
    for (int i = tid; i < 8 * 76; i += 256) {
        const int pr = i / 76, pc = i % 76;
        Vs[(72 + pr) * 76 + pc] = (pr == 0 && pc < 64) ? (f16)1.f : (f16)0.f;
    }

    // Q fragments (q pre-scaled by 1/sqrt(72) in qk_norm2); chunk2 zero-padded
    const f16* qrow0 = QKV + ((long)(bb * 1024 + q0 + w * 32 + l16)) * 3456 + h * 72;
    const f16* qrow1 = qrow0 + (long)16 * 3456;
    f16x8 qz = {};
    f16x8 qf[2][3];
    qf[0][0] = *(const f16x8*)(qrow0 + quad * 8);
    qf[0][1] = *(const f16x8*)(qrow0 + 32 + quad * 8);
    qf[0][2] = (quad == 0) ? *(const f16x8*)(qrow0 + 64) : qz;
    qf[1][0] = *(const f16x8*)(qrow1 + quad * 8);
    qf[1][1] = *(const f16x8*)(qrow1 + 32 + quad * 8);
    qf[1][2] = (quad == 0) ? *(const f16x8*)(qrow1 + 64) : qz;

    f32x4 o[2][5] = {};

    const f16* gK = Kc + (long)bh * S * 72;
    const f16* gV = Vt + (long)bh * 72 * S;

    for (int s0 = 0; s0 < S; s0 += 64) {
        for (int ch = w; ch < 9; ch += 4)
            gld16(gK + (long)s0 * 72 + ch * 512 + lane * 8,
                  &Ks[__builtin_amdgcn_readfirstlane(ch * 512)]);
#pragma unroll
        for (int it = 0; it < 3; ++it) {
            const int idx = it * 256 + tid;
            if (idx < 576) {
                const int d = idx >> 3, s8 = (idx & 7) * 8;
                f16x8 v = *(const f16x8*)(gV + (long)d * 1024 + s0 + s8);
                f16x4 lo = {v[0], v[1], v[2], v[3]};
                f16x4 hi = {v[4], v[5], v[6], v[7]};
                *(f16x4*)&Vs[d * 76 + s8] = lo;
                *(f16x4*)&Vs[d * 76 + s8 + 4] = hi;
            }
        }
        __syncthreads();

        // Sc^T[s][q] = K·Q^T : A=K-frag, B=Q-frag
        f32x4 sc[4][2] = {};
#pragma unroll
        for (int ss = 0; ss < 4; ++ss) {
            const int base = (ss * 16 + l16) * 72;
            f16x8 k0 = *(const f16x8*)&Ks[base + quad * 8];
            f16x8 k1 = *(const f16x8*)&Ks[base + 32 + quad * 8];
            f16x8 k2 = *(const f16x8*)&Ks[base + 64 + quad * 8];  // junk for quad>0: q-frag is 0
            sc[ss][0] = __builtin_amdgcn_mfma_f32_16x16x32_f16(k0, qf[0][0], sc[ss][0], 0, 0, 0);
            sc[ss][0] = __builtin_amdgcn_mfma_f32_16x16x32_f16(k1, qf[0][1], sc[ss][0], 0, 0, 0);
            sc[ss][0] = __builtin_amdgcn_mfma_f32_16x16x32_f16(k2, qf[0][2], sc[ss][0], 0, 0, 0);
            sc[ss][1] = __builtin_amdgcn_mfma_f32_16x16x32_f16(k0, qf[1][0], sc[ss][1], 0, 0, 0);
            sc[ss][1] = __builtin_amdgcn_mfma_f32_16x16x32_f16(k1, qf[1][1], sc[ss][1], 0, 0, 0);
            sc[ss][1] = __builtin_amdgcn_mfma_f32_16x16x32_f16(k2, qf[1][2], sc[ss][1], 0, 0, 0);
        }

        // p = exp(s) — no max subtraction: |s| <= sqrt(72) ~ 8.5, exp <= ~4900
        f16x4 pf[4][2];
#pragma unroll
        for (int ss = 0; ss < 4; ++ss)
#pragma unroll
            for (int qs = 0; qs < 2; ++qs) {
                f16x4 pk;
#pragma unroll
                for (int r = 0; r < 4; ++r) pk[r] = (f16)__expf(sc[ss][qs][r]);
                pf[ss][qs] = pk;
            }

        // O^T[d][q] += Vt_frag · P^T   (16x16x16, K = s)
#pragma unroll
        for (int vt = 0; vt < 5; ++vt) {
#pragma unroll
            for (int ss = 0; ss < 4; ++ss) {
                f16x4 vf = *(const f16x4*)&Vs[(vt * 16 + l16) * 76 + ss * 16 + quad * 4];
                o[0][vt] = __builtin_amdgcn_mfma_f32_16x16x16f16(vf, pf[ss][0], o[0][vt], 0, 0, 0);
                o[1][vt] = __builtin_amdgcn_mfma_f32_16x16x16f16(vf, pf[ss][1], o[1][vt], 0, 0, 0);
            }
        }
        __syncthreads();
    }

    // l lives at d==72 -> (vt=4, quad=2, r=0); broadcast per q column
    const float l0 = __shfl(o[0][4][0], 32 + l16);
    const float l1 = __shfl(o[1][4][0], 32 + l16);
    const float inv[2] = {1.f / l0, 1.f / l1};

    // transpose O^T -> O via per-wave LDS scratch (rows of 80), then coalesced stores
    f16* es = smem + w * 2560;  // 32 rows x 80
#pragma unroll
    for (int qs = 0; qs < 2; ++qs) {
        f16* row = es + (qs * 16 + l16) * 80;
#pragma unroll
        for (int vt = 0; vt < 5; ++vt)
#pragma unroll
            for (int r = 0; r < 4; ++r) {
                const int d = vt * 16 + quad * 4 + r;
                if (d < 72) row[d] = (f16)(o[qs][vt][r] * inv[qs]);
            }
    }
    const long rowbase = (long)bb * 1024 + q0 + w * 32;
#pragma unroll
    for (int it = 0; it < 5; ++it) {
        const int idx = it * 64 + lane;
        if (idx < 288) {
            const int q = idx / 9, c = idx - q * 9;
            f16x4 a = *(const f16x4*)&es[q * 80 + c * 8];
            f16x4 b2 = *(const f16x4*)&es[q * 80 + c * 8 + 4];
            f16* dst = O + (rowbase + q) * 1152 + h * 72 + c * 8;
            *(f16x4*)dst = a;
            *(f16x4*)(dst + 4) = b2;
        }
    }
}

extern "C" void kernel_launch(void* const* d_in, const int* in_sizes, int n_in,
                              void* d_out, int out_size, void* d_ws, size_t ws_size,
                              hipStream_t stream) {
    const float* x       = (const float*)d_in[0];
    const float* w_qkv   = (const float*)d_in[1];
    const float* b_qkv   = (const float*)d_in[2];
    const float* q_gamma = (const float*)d_in[3];
    const float* k_gamma = (const float*)d_in[4];
    const float* w_proj  = (const float*)d_in[5];
    const float* b_proj  = (const float*)d_in[6];
    float* out = (float*)d_out;

    char* p = (char*)d_ws;
    f16* x_h = (f16*)p;      p += (size_t)16384 * 1152 * 2;  // reused as ao after QKV GEMM
    f16* wqkv_h = (f16*)p;   p += (size_t)3456 * 1152 * 2;
    f16* wproj_h = (f16*)p;  p += (size_t)1152 * 1152 * 2;
    f16* qkv_h = (f16*)p;    p += (size_t)16384 * 3456 * 2;
    const size_t needed = (size_t)(p - (char*)d_ws);
    if (ws_size < needed) return;

    // d_out doubles as scratch until the final proj GEMM overwrites it:
    f16* k_c = (f16*)d_out;                        // [256][1024][72]
    f16* v_t = (f16*)d_out + (size_t)16384 * 1152; // [256][72][1024]

    f32_to_f16_vec<<<18432, 256, 0, stream>>>(x, x_h, 16384L * 1152 / 4);
    f32_to_f16_vec<<<3888, 256, 0, stream>>>(w_qkv, wqkv_h, 3456L * 1152 / 4);
    f32_to_f16_vec<<<1296, 256, 0, stream>>>(w_proj, wproj_h, 1152L * 1152 / 4);

    gemm_bt<<<27 * 128, 256, 0, stream>>>(
        x_h, wqkv_h, b_qkv, nullptr, qkv_h, 16384, 3456, 1152);

    qk_norm2<<<1024, 256, 0, stream>>>(qkv_h, q_gamma, k_gamma, k_c);
    vt_kernel<<<dim3(256, 16), 256, 0, stream>>>(qkv_h, v_t);

    attn2<<<2048, 256, 0, stream>>>(qkv_h, k_c, v_t, x_h /* ao */);

    gemm_bt<<<9 * 128, 256, 0, stream>>>(
        x_h, wproj_h, b_proj, out, nullptr, 16384, 1152, 1152);
}